// Round 8
// baseline (292.091 us; speedup 1.0000x reference)
//
#include <hip/hip_runtime.h>
#include <hip/hip_bf16.h>
#include <cmath>

#define T_SEQ 2048
#define NHEADS 16
#define DHEAD 64
#define DMODEL 1024
#define CQKV 3072

typedef __attribute__((ext_vector_type(8))) short short8;
typedef __attribute__((ext_vector_type(8))) __bf16 bf16x8;
typedef __attribute__((ext_vector_type(4))) float floatx4;

#define LDS_CAST(p) ((__attribute__((address_space(3))) void*)(p))
#define GLB_CAST(p) ((const __attribute__((address_space(1))) void*)(p))

static __device__ __forceinline__ floatx4 mfma_bf16(short8 a, short8 b, floatx4 c) {
  return __builtin_amdgcn_mfma_f32_16x16x32_bf16(
      __builtin_bit_cast(bf16x8, a), __builtin_bit_cast(bf16x8, b), c, 0, 0, 0);
}

// fp32 -> bf16 round-to-nearest-even, bit carrier = short
static __device__ __forceinline__ short f2bf(float f) {
  union { float f; unsigned u; } x; x.f = f;
  unsigned r = x.u + 0x7FFFu + ((x.u >> 16) & 1u);
  return (short)(r >> 16);
}

static __device__ __forceinline__ float bf2f(short s) {
  return __builtin_bit_cast(float, ((unsigned)(unsigned short)s) << 16);
}

static __device__ __forceinline__ float exp2_(float x) {
#if __has_builtin(__builtin_amdgcn_exp2f)
  return __builtin_amdgcn_exp2f(x);
#else
  return exp2f(x);
#endif
}

// bf16 vs fp32 input sniff (round-1 notes). 16-of-32 exponent vote.
static __device__ __forceinline__ bool sniff_is_bf16(const unsigned* __restrict__ x) {
  int cnt = 0;
#pragma unroll
  for (int i = 0; i < 32; ++i) {
    unsigned e = (x[i] >> 7) & 0xFFu;
    cnt += (e >= 0x70u && e <= 0x8Fu) ? 1 : 0;
  }
  return cnt >= 16;
}

static __device__ __forceinline__ short8 load8f32(const char* p, size_t idx) {
  const float4* f = (const float4*)(p + idx * 4);
  float4 a = f[0], b = f[1];
  short8 r;
  r[0] = f2bf(a.x); r[1] = f2bf(a.y); r[2] = f2bf(a.z); r[3] = f2bf(a.w);
  r[4] = f2bf(b.x); r[5] = f2bf(b.y); r[6] = f2bf(b.z); r[7] = f2bf(b.w);
  return r;
}

// ---- preprocessing: x -> bf16 copy/convert --------------------------------
__global__ __launch_bounds__(256) void conv_x(const char* __restrict__ x,
                                              short* __restrict__ o, int n,
                                              const unsigned* __restrict__ xs) {
  const bool isbf = sniff_is_bf16(xs);
  const int i = (blockIdx.x * 256 + threadIdx.x) * 8;
  if (i >= n) return;
  if (isbf) *(short8*)(o + i) = *(const short8*)((const short*)x + i);
  else      *(short8*)(o + i) = load8f32(x, (size_t)i);
}

// ---- preprocessing: W [K][N] -> W^T [N][K] bf16 ---------------------------
__global__ __launch_bounds__(256) void tpose(const char* __restrict__ w,
                                             short* __restrict__ wt, int K, int N,
                                             const unsigned* __restrict__ xs) {
  const bool isbf = sniff_is_bf16(xs);
  __shared__ short tile[32][33];
  const int n0 = blockIdx.x * 32, k0 = blockIdx.y * 32;
  const int tx = threadIdx.x & 31, ty = threadIdx.x >> 5;  // 32 x 8
#pragma unroll
  for (int i = 0; i < 4; ++i) {
    const int r = ty * 4 + i;
    const size_t off = (size_t)(k0 + r) * N + n0 + tx;
    tile[r][tx] = isbf ? ((const short*)w)[off] : f2bf(((const float*)w)[off]);
  }
  __syncthreads();
#pragma unroll
  for (int i = 0; i < 4; ++i) {
    const int r = ty * 4 + i;
    wt[(size_t)(n0 + r) * K + k0 + tx] = tile[tx][r];
  }
}

// ---- m97-style GEMM: C = A @ Bt^T, 128x128 tile, BK=32, XOR-swizzled LDS --
// mode 0: C bf16 row-major [M,N]
// mode 1: C dtype per sniff (bf16 in -> bf16 out, fp32 in -> fp32 out)
// mode 2: QKV split: cols [0,2048) -> qk [M,2048]; cols [2048,3072) -> vT.
__global__ __launch_bounds__(256) void gemm128(const short* __restrict__ A,
                                               const short* __restrict__ Bt,
                                               void* __restrict__ C,
                                               short* __restrict__ C2,
                                               int M, int N, int K, int mode,
                                               const unsigned* __restrict__ xs) {
  const bool out_f32 = (mode == 1) ? !sniff_is_bf16(xs) : false;

  __shared__ short as[128 * 32];
  __shared__ short bs[128 * 32];
  const int tid = threadIdx.x;
  const int wid = tid >> 6, lane = tid & 63;
  const int quad = lane >> 4, l16 = lane & 15;
  const int wm = wid >> 1, wn = wid & 1;
  const int m0 = blockIdx.y * 128, n0 = blockIdx.x * 128;

  // staging: wave covers 16 rows x 32k; 4 lanes/row, 16B chunks XOR-swizzled
  const int srow = wid * 16 + (lane >> 2);
  const int skc = ((lane & 3) ^ ((lane >> 2) & 3)) * 8;  // swizzle key = row&3

  const floatx4 zero4 = {0.f, 0.f, 0.f, 0.f};
  floatx4 acc[4][4];
#pragma unroll
  for (int i = 0; i < 4; ++i)
#pragma unroll
    for (int j = 0; j < 4; ++j) acc[i][j] = zero4;

  // fragment read slot: chunk quad of row R lives at slot quad ^ (R&3)
  const int rslot = (quad ^ (l16 & 3)) * 8;

  for (int kt = 0; kt < K; kt += 32) {
    __syncthreads();
#pragma unroll
    for (int r = 0; r < 2; ++r) {
      const short* ga = A + (size_t)(m0 + r * 64 + srow) * K + kt + skc;
      const short* gb = Bt + (size_t)(n0 + r * 64 + srow) * K + kt + skc;
      __builtin_amdgcn_global_load_lds(GLB_CAST(ga), LDS_CAST(as + r * 2048 + wid * 512), 16, 0, 0);
      __builtin_amdgcn_global_load_lds(GLB_CAST(gb), LDS_CAST(bs + r * 2048 + wid * 512), 16, 0, 0);
    }
    __syncthreads();

    short8 afr[4], bfr[4];
#pragma unroll
    for (int mt = 0; mt < 4; ++mt)
      afr[mt] = *(const short8*)&as[(wm * 64 + mt * 16 + l16) * 32 + rslot];
#pragma unroll
    for (int nt = 0; nt < 4; ++nt)
      bfr[nt] = *(const short8*)&bs[(wn * 64 + nt * 16 + l16) * 32 + rslot];
#pragma unroll
    for (int mt = 0; mt < 4; ++mt)
#pragma unroll
      for (int nt = 0; nt < 4; ++nt)
        acc[mt][nt] = mfma_bf16(afr[mt], bfr[nt], acc[mt][nt]);
  }

  const int row0 = m0 + wm * 64 + quad * 4;
  const int col0 = n0 + wn * 64 + l16;
  if (mode == 2 && n0 >= 2048) {
    // V part -> transposed vT[(b*16+h)*64+d][t]
#pragma unroll
    for (int mt = 0; mt < 4; ++mt)
#pragma unroll
      for (int nt = 0; nt < 4; ++nt)
#pragma unroll
        for (int r = 0; r < 4; ++r) {
          const int row = row0 + mt * 16 + r;
          const int col = col0 + nt * 16;
          const int d = col & 63, hh = (col >> 6) - 32;
          const int bb = row >> 11, t = row & 2047;
          C2[((size_t)(bb * 16 + hh) * 64 + d) * T_SEQ + t] = f2bf(acc[mt][nt][r]);
        }
  } else {
    const int outN = (mode == 2) ? 2048 : N;
#pragma unroll
    for (int mt = 0; mt < 4; ++mt)
#pragma unroll
      for (int nt = 0; nt < 4; ++nt)
#pragma unroll
        for (int r = 0; r < 4; ++r) {
          const size_t off = (size_t)(row0 + mt * 16 + r) * outN + col0 + nt * 16;
          if (out_f32) ((float*)C)[off] = acc[mt][nt][r];
          else         ((short*)C)[off] = f2bf(acc[mt][nt][r]);
        }
  }
}

// ---- flash attention: 128 q/block, 2 q-tiles/wave, UNIFORM control flow ---
// qk [b*2048+t][2048] (Q cols 0..1023, K cols 1024..2047), vT [(b*16+h)*64+d][t].
// Both q-tiles processed every iteration (tile 0's post-diagonal iteration is
// fully masked -> contributes exactly 0). K/V B-frags shared by both tiles.
__global__ __launch_bounds__(256) void attn(const short* __restrict__ qk,
                                            const short* __restrict__ vT,
                                            short* __restrict__ y) {
  __shared__ short ks[64 * 64];       // [key][d], 8 chunks/row XOR-swizzled
  __shared__ short vs[64 * 64];       // [d][key], same swizzle
  __shared__ short ps[4][2][16][72];  // per-wave, per-q-tile P [q][key]
  const int tid = threadIdx.x;
  const int wid = tid >> 6, lane = tid & 63;
  const int quad = lane >> 4, l16 = lane & 15;
  const int b = blockIdx.x >> 4, h = blockIdx.x & 15;
  const int q0 = ((int)gridDim.y - 1 - (int)blockIdx.y) * 128;  // heavy first
  const int qw[2] = {q0 + wid * 16, q0 + 64 + wid * 16};

  const short* qbase = qk + (size_t)b * T_SEQ * 2048 + h * DHEAD;
  const short* kbase = qbase + DMODEL;
  const short* vtb = vT + (size_t)(b * NHEADS + h) * DHEAD * T_SEQ;
  const float SC = 0.18033688011112042f;  // 0.125 * log2(e), folded into Q

  // Q fragments (A-layout m=l16, k=quad*8+j), pre-scaled by SC
  short8 aq[2][2];
#pragma unroll
  for (int t = 0; t < 2; ++t)
#pragma unroll
    for (int kc = 0; kc < 2; ++kc) {
      short8 raw = *(const short8*)(qbase + (size_t)(qw[t] + l16) * 2048 + kc * 32 + quad * 8);
#pragma unroll
      for (int j = 0; j < 8; ++j) aq[t][kc][j] = f2bf(bf2f(raw[j]) * SC);
    }

  const floatx4 zero4 = {0.f, 0.f, 0.f, 0.f};
  floatx4 o[2][4], lacc[2] = {zero4, zero4};
#pragma unroll
  for (int t = 0; t < 2; ++t)
#pragma unroll
    for (int i = 0; i < 4; ++i) o[t][i] = zero4;
  const short8 ones8 = {0x3F80, 0x3F80, 0x3F80, 0x3F80, 0x3F80, 0x3F80, 0x3F80, 0x3F80};

  // staging lane map: row = i*32 + wid*8 + (lane>>3), chunk = (lane&7) ^ (row&7)
  const int srl = lane >> 3;
  const int sch = ((lane & 7) ^ srl) * 8;

  const int kend = q0 + 128;
  for (int kt = 0; kt < kend; kt += 64) {
    __syncthreads();  // prev iteration's LDS readers done
#pragma unroll
    for (int i = 0; i < 2; ++i) {
      const int row = i * 32 + wid * 8 + srl;
      const short* gk = kbase + (size_t)(kt + row) * 2048 + sch;
      const short* gv = vtb + (size_t)row * T_SEQ + kt + sch;
      __builtin_amdgcn_global_load_lds(GLB_CAST(gk), LDS_CAST(ks + (i * 32 + wid * 8) * 64), 16, 0, 0);
      __builtin_amdgcn_global_load_lds(GLB_CAST(gv), LDS_CAST(vs + (i * 32 + wid * 8) * 64), 16, 0, 0);
    }
    __syncthreads();  // DMA drained

    // K B-frags read once, shared by both q-tiles
    short8 bk[2][4];
#pragma unroll
    for (int kc = 0; kc < 2; ++kc)
#pragma unroll
      for (int nt = 0; nt < 4; ++nt) {
        const int slot = ((kc * 4 + quad) ^ (l16 & 7)) * 8;
        bk[kc][nt] = *(const short8*)&ks[(nt * 16 + l16) * 64 + slot];
      }

    // S = Q K^T, max-free exp2 softmax, P -> per-wave-per-tile LDS
#pragma unroll
    for (int t = 0; t < 2; ++t) {
      floatx4 s[4];
#pragma unroll
      for (int nt = 0; nt < 4; ++nt) {
        s[nt] = zero4;
#pragma unroll
        for (int kc = 0; kc < 2; ++kc) s[nt] = mfma_bf16(aq[t][kc], bk[kc][nt], s[nt]);
      }
      const bool full = (kt + 63 <= qw[t]);  // wave-uniform
#pragma unroll
      for (int nt = 0; nt < 4; ++nt)
#pragma unroll
        for (int r = 0; r < 4; ++r) {
          float p = exp2_(s[nt][r]);
          if (!full) {
            const int key = kt + nt * 16 + l16;
            const int q = qw[t] + quad * 4 + r;
            p = (key <= q) ? p : 0.f;
          }
          s[nt][r] = p;
        }
#pragma unroll
      for (int nt = 0; nt < 4; ++nt)
#pragma unroll
        for (int r = 0; r < 4; ++r)
          ps[wid][t][quad * 4 + r][nt * 16 + l16] = f2bf(s[nt][r]);
    }

    __syncthreads();  // defensive: drain P writes before P reads (uniform flow)

    // O += P V ; l += P 1  (V B-frags shared by both q-tiles)
#pragma unroll
    for (int kc = 0; kc < 2; ++kc) {
      short8 ap[2];
#pragma unroll
      for (int t = 0; t < 2; ++t) {
        ap[t] = *(const short8*)&ps[wid][t][l16][kc * 32 + quad * 8];
        lacc[t] = mfma_bf16(ap[t], ones8, lacc[t]);
      }
#pragma unroll
      for (int d4 = 0; d4 < 4; ++d4) {
        const int slot = ((kc * 4 + quad) ^ (l16 & 7)) * 8;
        const short8 bv = *(const short8*)&vs[(d4 * 16 + l16) * 64 + slot];
#pragma unroll
        for (int t = 0; t < 2; ++t) o[t][d4] = mfma_bf16(ap[t], bv, o[t][d4]);
      }
    }
  }

  // epilogue: O /= l
#pragma unroll
  for (int t = 0; t < 2; ++t) {
    floatx4 inv;
#pragma unroll
    for (int r = 0; r < 4; ++r) inv[r] = 1.0f / lacc[t][r];
#pragma unroll
    for (int d4 = 0; d4 < 4; ++d4)
#pragma unroll
      for (int r = 0; r < 4; ++r) {
        const int q = qw[t] + quad * 4 + r;
        y[(size_t)(b * T_SEQ + q) * DMODEL + h * DHEAD + d4 * 16 + l16] =
            f2bf(o[t][d4][r] * inv[r]);
      }
  }
}

extern "C" void kernel_launch(void* const* d_in, const int* in_sizes, int n_in,
                              void* d_out, int out_size, void* d_ws, size_t ws_size,
                              hipStream_t stream) {
  const char* x = (const char*)d_in[0];       // [4,2048,1024] fp32 (or bf16)
  const char* w_qkv = (const char*)d_in[1];   // [1024,3072]
  const char* w_proj = (const char*)d_in[2];  // [1024,1024]
  const unsigned* xs = (const unsigned*)d_in[0];

  // ws: qk(33.6M) | vT(16.8M) | wqkvT(6.3M) | wprojT(2.1M) | xbf=ybuf(16.8M) = 75.5MB
  short* qk = (short*)d_ws;                          // 8192*2048
  short* vTb = qk + (size_t)8192 * 2048;             // 64*64*2048
  short* wqkvT = vTb + (size_t)64 * 64 * 2048;       // 3072*1024
  short* wprojT = wqkvT + (size_t)3072 * 1024;       // 1024*1024
  short* xbf = wprojT + (size_t)1024 * 1024;         // 8192*1024
  short* ybuf = xbf;                                 // alias: xbf dead after gemm1

  conv_x<<<8192 * 1024 / (256 * 8), 256, 0, stream>>>(x, xbf, 8192 * 1024, xs);
  {
    dim3 g1(3072 / 32, 1024 / 32);
    tpose<<<g1, 256, 0, stream>>>(w_qkv, wqkvT, 1024, 3072, xs);
    dim3 g2(1024 / 32, 1024 / 32);
    tpose<<<g2, 256, 0, stream>>>(w_proj, wprojT, 1024, 1024, xs);
  }
  {  // qkv projection with split epilogue: Q,K -> qk ; V -> vT (transposed)
    dim3 grid(3072 / 128, 8192 / 128);
    gemm128<<<grid, 256, 0, stream>>>(xbf, wqkvT, qk, vTb, 8192, 3072, 1024, 2, xs);
  }
  {
    dim3 grid(4 * NHEADS, T_SEQ / 128);
    attn<<<grid, 256, 0, stream>>>(qk, vTb, ybuf);
  }
  {
    dim3 grid(1024 / 128, 8192 / 128);
    gemm128<<<grid, 256, 0, stream>>>(ybuf, wprojT, d_out, nullptr, 8192, 1024, 1024, 1, xs);
  }
}

// Round 9
// 269.446 us; speedup vs baseline: 1.0840x; 1.0840x over previous
//
#include <hip/hip_runtime.h>
#include <hip/hip_bf16.h>
#include <cmath>

#define T_SEQ 2048
#define NHEADS 16
#define DHEAD 64
#define DMODEL 1024
#define CQKV 3072

typedef __attribute__((ext_vector_type(8))) short short8;
typedef __attribute__((ext_vector_type(8))) __bf16 bf16x8;
typedef __attribute__((ext_vector_type(4))) float floatx4;

#define LDS_CAST(p) ((__attribute__((address_space(3))) void*)(p))
#define GLB_CAST(p) ((const __attribute__((address_space(1))) void*)(p))

static __device__ __forceinline__ floatx4 mfma_bf16(short8 a, short8 b, floatx4 c) {
  return __builtin_amdgcn_mfma_f32_16x16x32_bf16(
      __builtin_bit_cast(bf16x8, a), __builtin_bit_cast(bf16x8, b), c, 0, 0, 0);
}

// fp32 -> bf16 round-to-nearest-even, bit carrier = short
static __device__ __forceinline__ short f2bf(float f) {
  union { float f; unsigned u; } x; x.f = f;
  unsigned r = x.u + 0x7FFFu + ((x.u >> 16) & 1u);
  return (short)(r >> 16);
}

static __device__ __forceinline__ float bf2f(short s) {
  return __builtin_bit_cast(float, ((unsigned)(unsigned short)s) << 16);
}

static __device__ __forceinline__ float exp2_(float x) {
#if __has_builtin(__builtin_amdgcn_exp2f)
  return __builtin_amdgcn_exp2f(x);
#else
  return exp2f(x);
#endif
}

// bf16 vs fp32 input sniff (round-1 notes). 16-of-32 exponent vote.
static __device__ __forceinline__ bool sniff_is_bf16(const unsigned* __restrict__ x) {
  int cnt = 0;
#pragma unroll
  for (int i = 0; i < 32; ++i) {
    unsigned e = (x[i] >> 7) & 0xFFu;
    cnt += (e >= 0x70u && e <= 0x8Fu) ? 1 : 0;
  }
  return cnt >= 16;
}

static __device__ __forceinline__ short8 load8f32(const char* p, size_t idx) {
  const float4* f = (const float4*)(p + idx * 4);
  float4 a = f[0], b = f[1];
  short8 r;
  r[0] = f2bf(a.x); r[1] = f2bf(a.y); r[2] = f2bf(a.z); r[3] = f2bf(a.w);
  r[4] = f2bf(b.x); r[5] = f2bf(b.y); r[6] = f2bf(b.z); r[7] = f2bf(b.w);
  return r;
}

// ---- preprocessing: x -> bf16 copy/convert --------------------------------
__global__ __launch_bounds__(256) void conv_x(const char* __restrict__ x,
                                              short* __restrict__ o, int n,
                                              const unsigned* __restrict__ xs) {
  const bool isbf = sniff_is_bf16(xs);
  const int i = (blockIdx.x * 256 + threadIdx.x) * 8;
  if (i >= n) return;
  if (isbf) *(short8*)(o + i) = *(const short8*)((const short*)x + i);
  else      *(short8*)(o + i) = load8f32(x, (size_t)i);
}

// ---- preprocessing: W [K][N] -> W^T [N][K] bf16 ---------------------------
__global__ __launch_bounds__(256) void tpose(const char* __restrict__ w,
                                             short* __restrict__ wt, int K, int N,
                                             const unsigned* __restrict__ xs) {
  const bool isbf = sniff_is_bf16(xs);
  __shared__ short tile[32][33];
  const int n0 = blockIdx.x * 32, k0 = blockIdx.y * 32;
  const int tx = threadIdx.x & 31, ty = threadIdx.x >> 5;  // 32 x 8
#pragma unroll
  for (int i = 0; i < 4; ++i) {
    const int r = ty * 4 + i;
    const size_t off = (size_t)(k0 + r) * N + n0 + tx;
    tile[r][tx] = isbf ? ((const short*)w)[off] : f2bf(((const float*)w)[off]);
  }
  __syncthreads();
#pragma unroll
  for (int i = 0; i < 4; ++i) {
    const int r = ty * 4 + i;
    wt[(size_t)(n0 + r) * K + k0 + tx] = tile[tx][r];
  }
}

// ---- GEMM: C = A @ Bt^T, 128x128 tile, BK=64, XOR-swizzled LDS ------------
// BK=64 halves barrier count vs BK=32 (K=1024 -> 16 iters); LDS 32KB -> 5 blk/CU.
// mode 0: C bf16 row-major [M,N]
// mode 1: C dtype per sniff (bf16 in -> bf16 out, fp32 in -> fp32 out)
// mode 2: QKV split: cols [0,2048) -> qk [M,2048]; cols [2048,3072) -> vT.
__global__ __launch_bounds__(256) void gemm128(const short* __restrict__ A,
                                               const short* __restrict__ Bt,
                                               void* __restrict__ C,
                                               short* __restrict__ C2,
                                               int M, int N, int K, int mode,
                                               const unsigned* __restrict__ xs) {
  const bool out_f32 = (mode == 1) ? !sniff_is_bf16(xs) : false;

  __shared__ short as[128 * 64];
  __shared__ short bs[128 * 64];
  const int tid = threadIdx.x;
  const int wid = tid >> 6, lane = tid & 63;
  const int quad = lane >> 4, l16 = lane & 15;
  const int wm = wid >> 1, wn = wid & 1;
  const int m0 = blockIdx.y * 128, n0 = blockIdx.x * 128;

  // staging: issue i of wave covers rows wid*32 + i*8 .. +8 (128B rows)
  const int srl = lane >> 3;               // row within the 8-row group
  const int sch = ((lane & 7) ^ srl) * 8;  // XOR-swizzled 16B chunk (shorts)

  const floatx4 zero4 = {0.f, 0.f, 0.f, 0.f};
  floatx4 acc[4][4];
#pragma unroll
  for (int i = 0; i < 4; ++i)
#pragma unroll
    for (int j = 0; j < 4; ++j) acc[i][j] = zero4;

  for (int kt = 0; kt < K; kt += 64) {
    __syncthreads();
#pragma unroll
    for (int i = 0; i < 4; ++i) {
      const int row = wid * 32 + i * 8;
      const short* ga = A + (size_t)(m0 + row + srl) * K + kt + sch;
      const short* gb = Bt + (size_t)(n0 + row + srl) * K + kt + sch;
      __builtin_amdgcn_global_load_lds(GLB_CAST(ga), LDS_CAST(as + row * 64), 16, 0, 0);
      __builtin_amdgcn_global_load_lds(GLB_CAST(gb), LDS_CAST(bs + row * 64), 16, 0, 0);
    }
    __syncthreads();

    // fragment slot: chunk j of row R lives at slot j ^ (R&7); R&7 == l16&7
#pragma unroll
    for (int kc = 0; kc < 2; ++kc) {
      const int slot = ((kc * 4 + quad) ^ (l16 & 7)) * 8;
      short8 afr[4], bfr[4];
#pragma unroll
      for (int mt = 0; mt < 4; ++mt)
        afr[mt] = *(const short8*)&as[(wm * 64 + mt * 16 + l16) * 64 + slot];
#pragma unroll
      for (int nt = 0; nt < 4; ++nt)
        bfr[nt] = *(const short8*)&bs[(wn * 64 + nt * 16 + l16) * 64 + slot];
#pragma unroll
      for (int mt = 0; mt < 4; ++mt)
#pragma unroll
        for (int nt = 0; nt < 4; ++nt)
          acc[mt][nt] = mfma_bf16(afr[mt], bfr[nt], acc[mt][nt]);
    }
  }

  const int row0 = m0 + wm * 64 + quad * 4;
  const int col0 = n0 + wn * 64 + l16;
  if (mode == 2 && n0 >= 2048) {
    // V part -> transposed vT[(b*16+h)*64+d][t]
#pragma unroll
    for (int mt = 0; mt < 4; ++mt)
#pragma unroll
      for (int nt = 0; nt < 4; ++nt)
#pragma unroll
        for (int r = 0; r < 4; ++r) {
          const int row = row0 + mt * 16 + r;
          const int col = col0 + nt * 16;
          const int d = col & 63, hh = (col >> 6) - 32;
          const int bb = row >> 11, t = row & 2047;
          C2[((size_t)(bb * 16 + hh) * 64 + d) * T_SEQ + t] = f2bf(acc[mt][nt][r]);
        }
  } else {
    const int outN = (mode == 2) ? 2048 : N;
#pragma unroll
    for (int mt = 0; mt < 4; ++mt)
#pragma unroll
      for (int nt = 0; nt < 4; ++nt)
#pragma unroll
        for (int r = 0; r < 4; ++r) {
          const size_t off = (size_t)(row0 + mt * 16 + r) * outN + col0 + nt * 16;
          if (out_f32) ((float*)C)[off] = acc[mt][nt][r];
          else         ((short*)C)[off] = f2bf(acc[mt][nt][r]);
        }
  }
}

// ---- flash attention (round-6 validated version, reverted verbatim) -------
// qk [b*2048+t][2048] (Q cols 0..1023, K cols 1024..2047), vT [(b*16+h)*64+d][t].
// Block = 4 waves x 16 queries; BK=64. K/V tiles shared by all 4 waves.
__global__ __launch_bounds__(256) void attn(const short* __restrict__ qk,
                                            const short* __restrict__ vT,
                                            short* __restrict__ y) {
  __shared__ short ks[64 * 64];    // [key][d], 8 chunks/row XOR-swizzled
  __shared__ short vs[64 * 64];    // [d][key], same swizzle
  __shared__ short ps[4][16][72];  // per-wave P [q][key]
  const int tid = threadIdx.x;
  const int wid = tid >> 6, lane = tid & 63;
  const int quad = lane >> 4, l16 = lane & 15;
  const int b = blockIdx.x >> 4, h = blockIdx.x & 15;
  const int q0 = ((int)gridDim.y - 1 - (int)blockIdx.y) * 64;  // heavy blocks first
  const int qw0 = q0 + wid * 16;

  const short* qbase = qk + (size_t)b * T_SEQ * 2048 + h * DHEAD;
  const short* kbase = qbase + DMODEL;
  const short* vtb = vT + (size_t)(b * NHEADS + h) * DHEAD * T_SEQ;
  const float SC = 0.18033688011112042f;  // 0.125 * log2(e), folded into Q

  // Q fragments (A-layout m=l16, k=quad*8+j), pre-scaled by SC
  short8 aq[2];
#pragma unroll
  for (int kc = 0; kc < 2; ++kc) {
    short8 raw = *(const short8*)(qbase + (size_t)(qw0 + l16) * 2048 + kc * 32 + quad * 8);
#pragma unroll
    for (int j = 0; j < 8; ++j) aq[kc][j] = f2bf(bf2f(raw[j]) * SC);
  }

  const floatx4 zero4 = {0.f, 0.f, 0.f, 0.f};
  floatx4 o[4], lacc = zero4;  // lacc: row-sum via ones-MFMA
#pragma unroll
  for (int i = 0; i < 4; ++i) o[i] = zero4;
  const short8 ones8 = {0x3F80, 0x3F80, 0x3F80, 0x3F80, 0x3F80, 0x3F80, 0x3F80, 0x3F80};

  // staging lane map: row = i*32 + wid*8 + (lane>>3), chunk = (lane&7) ^ (row&7)
  const int srl = lane >> 3;
  const int sch = ((lane & 7) ^ srl) * 8;

  const int kend = q0 + 64;
  for (int kt = 0; kt < kend; kt += 64) {
    __syncthreads();  // prev iteration's LDS readers done
#pragma unroll
    for (int i = 0; i < 2; ++i) {
      const int row = i * 32 + wid * 8 + srl;
      const short* gk = kbase + (size_t)(kt + row) * 2048 + sch;
      const short* gv = vtb + (size_t)row * T_SEQ + kt + sch;
      __builtin_amdgcn_global_load_lds(GLB_CAST(gk), LDS_CAST(ks + (i * 32 + wid * 8) * 64), 16, 0, 0);
      __builtin_amdgcn_global_load_lds(GLB_CAST(gv), LDS_CAST(vs + (i * 32 + wid * 8) * 64), 16, 0, 0);
    }
    __syncthreads();  // DMA drained

    // S = Q K^T : 16q x 64key per wave; B-frag chunk kc*4+quad at swizzled slot
    floatx4 s[4];
#pragma unroll
    for (int nt = 0; nt < 4; ++nt) {
      s[nt] = zero4;
#pragma unroll
      for (int kc = 0; kc < 2; ++kc) {
        const int slot = ((kc * 4 + quad) ^ (l16 & 7)) * 8;
        const short8 bk = *(const short8*)&ks[(nt * 16 + l16) * 64 + slot];
        s[nt] = mfma_bf16(aq[kc], bk, s[nt]);
      }
    }

    // max-free softmax: p = 2^s; zero masked keys (diagonal tiles only)
    const bool full = (kt + 63 <= qw0);  // wave-uniform
#pragma unroll
    for (int nt = 0; nt < 4; ++nt)
#pragma unroll
      for (int r = 0; r < 4; ++r) {
        float p = exp2_(s[nt][r]);
        if (!full) {
          const int key = kt + nt * 16 + l16;
          const int q = qw0 + quad * 4 + r;
          p = (key <= q) ? p : 0.f;
        }
        s[nt][r] = p;
      }

    // P (C-layout) -> per-wave LDS [q][key] (wave-internal, no barrier)
#pragma unroll
    for (int nt = 0; nt < 4; ++nt)
#pragma unroll
      for (int r = 0; r < 4; ++r)
        ps[wid][quad * 4 + r][nt * 16 + l16] = f2bf(s[nt][r]);

    // O += P V ; l += P 1
#pragma unroll
    for (int kc = 0; kc < 2; ++kc) {
      const short8 ap = *(const short8*)&ps[wid][l16][kc * 32 + quad * 8];
      lacc = mfma_bf16(ap, ones8, lacc);
#pragma unroll
      for (int d4 = 0; d4 < 4; ++d4) {
        const int slot = ((kc * 4 + quad) ^ (l16 & 7)) * 8;
        const short8 bv = *(const short8*)&vs[(d4 * 16 + l16) * 64 + slot];
        o[d4] = mfma_bf16(ap, bv, o[d4]);
      }
    }
  }

  // epilogue: O /= l
  floatx4 inv;
#pragma unroll
  for (int r = 0; r < 4; ++r) inv[r] = 1.0f / lacc[r];
#pragma unroll
  for (int d4 = 0; d4 < 4; ++d4)
#pragma unroll
    for (int r = 0; r < 4; ++r) {
      const int q = qw0 + quad * 4 + r;
      y[(size_t)(b * T_SEQ + q) * DMODEL + h * DHEAD + d4 * 16 + l16] =
          f2bf(o[d4][r] * inv[r]);
    }
}

extern "C" void kernel_launch(void* const* d_in, const int* in_sizes, int n_in,
                              void* d_out, int out_size, void* d_ws, size_t ws_size,
                              hipStream_t stream) {
  const char* x = (const char*)d_in[0];       // [4,2048,1024] fp32 (or bf16)
  const char* w_qkv = (const char*)d_in[1];   // [1024,3072]
  const char* w_proj = (const char*)d_in[2];  // [1024,1024]
  const unsigned* xs = (const unsigned*)d_in[0];

  // ws: qk(33.6M) | vT(16.8M) | wqkvT(6.3M) | wprojT(2.1M) | xbf=ybuf(16.8M) = 75.5MB
  short* qk = (short*)d_ws;                          // 8192*2048
  short* vTb = qk + (size_t)8192 * 2048;             // 64*64*2048
  short* wqkvT = vTb + (size_t)64 * 64 * 2048;       // 3072*1024
  short* wprojT = wqkvT + (size_t)3072 * 1024;       // 1024*1024
  short* xbf = wprojT + (size_t)1024 * 1024;         // 8192*1024
  short* ybuf = xbf;                                 // alias: xbf dead after gemm1

  conv_x<<<8192 * 1024 / (256 * 8), 256, 0, stream>>>(x, xbf, 8192 * 1024, xs);
  {
    dim3 g1(3072 / 32, 1024 / 32);
    tpose<<<g1, 256, 0, stream>>>(w_qkv, wqkvT, 1024, 3072, xs);
    dim3 g2(1024 / 32, 1024 / 32);
    tpose<<<g2, 256, 0, stream>>>(w_proj, wprojT, 1024, 1024, xs);
  }
  {  // qkv projection with split epilogue: Q,K -> qk ; V -> vT (transposed)
    dim3 grid(3072 / 128, 8192 / 128);
    gemm128<<<grid, 256, 0, stream>>>(xbf, wqkvT, qk, vTb, 8192, 3072, 1024, 2, xs);
  }
  {
    dim3 grid(4 * NHEADS, T_SEQ / 64);
    attn<<<grid, 256, 0, stream>>>(qk, vTb, ybuf);
  }
  {
    dim3 grid(1024 / 128, 8192 / 128);
    gemm128<<<grid, 256, 0, stream>>>(ybuf, wprojT, d_out, nullptr, 8192, 1024, 1024, 1, xs);
  }
}